// Round 9
// baseline (337603.394 us; speedup 1.0000x reference)
//
#include <hip/hip_runtime.h>
#include <math.h>

// Problem constants
#define LSEQ 1024   // seq len
#define NB   32     // batch
#define IC   256    // input size
#define HC   256    // hidden size
#define G4   1024   // 4*H
#define D2   512    // 2*H
#define TOPK 3

// d_ws layout:
//   [0, PRESZ)        pre_f (L,B,4H) floats
//   [PRESZ, 2*PRESZ)  pre_b
//   then 512 ints: xcc_arr[256] ++ flags[256]
#define PRESZ ((size_t)LSEQ * NB * G4)
#define SYNC_INT_OFF (2 * PRESZ)

// d_out layout (floats): coo (B,2,L*K) | vals (B,L,K) | lstm_out (B,L,2H)
#define COO_OFF  0
#define VALS_OFF ((size_t)NB * 2 * LSEQ * TOPK)
#define LSTM_OFF (VALS_OFF + (size_t)NB * LSEQ * TOPK)

#define ALIGN_SCALE 0.04419417382415922f  // 1/sqrt(512)

// HW_REG_XCC_ID read: s_getreg imm = ((size-1)<<11) | (offset<<6) | id
// id=20 (XCC_ID, gfx940+), offset=0, size=4  ->  (3<<11)|20 = 6164.
#define GETREG_XCC_IMM 6164

// Bounded-spin insurance: normal fast-path waits are <100 polls; 4096 gives
// ~40x margin while capping a broken-sc0 worst case at ~0.4ms/step.
#define SPIN_LIMIT 4096

// ---------------------------------------------------------------------------
// Zero the sync region (ws is re-poisoned 0xAA before every timed launch).
// ---------------------------------------------------------------------------
__global__ void zero_sync_kernel(int* __restrict__ p) {
    p[threadIdx.x] = 0;
}

// ---------------------------------------------------------------------------
// Kernel A: input projection  pre[d][l,b,g] = x[l,b,:]·w_ih[d][g,:] + bias[g]
// GEMM M=32768, N=1024, K=256 (NT). BM=BN=128, BK=16, 256 thr, 8x8 acc.
// ---------------------------------------------------------------------------
__global__ __launch_bounds__(256) void proj_kernel(
    const float* __restrict__ x,
    const float* __restrict__ w_f, const float* __restrict__ b_f,
    const float* __restrict__ w_b, const float* __restrict__ b_b,
    float* __restrict__ ws) {
    const int dir = blockIdx.z;
    const float* __restrict__ w    = dir ? w_b : w_f;
    const float* __restrict__ bias = dir ? b_b : b_f;
    float* __restrict__ pre = ws + (size_t)dir * PRESZ;

    const int m0 = blockIdx.x * 128;
    const int n0 = blockIdx.y * 128;
    const int tid = threadIdx.x;
    const int tx = tid & 15, ty = tid >> 4;

    __shared__ __align__(16) float As[16][132];
    __shared__ __align__(16) float Bs[16][132];

    float acc[8][8];
#pragma unroll
    for (int i = 0; i < 8; ++i)
#pragma unroll
        for (int j = 0; j < 8; ++j) acc[i][j] = 0.f;

    for (int k0 = 0; k0 < IC; k0 += 16) {
#pragma unroll
        for (int r = 0; r < 2; ++r) {
            const int e = r * 256 + tid;
            const int row = e >> 2, kq = e & 3;
            float4 va = *(const float4*)&x[(size_t)(m0 + row) * IC + k0 + kq * 4];
            As[kq * 4 + 0][row] = va.x; As[kq * 4 + 1][row] = va.y;
            As[kq * 4 + 2][row] = va.z; As[kq * 4 + 3][row] = va.w;
            float4 vb = *(const float4*)&w[(size_t)(n0 + row) * IC + k0 + kq * 4];
            Bs[kq * 4 + 0][row] = vb.x; Bs[kq * 4 + 1][row] = vb.y;
            Bs[kq * 4 + 2][row] = vb.z; Bs[kq * 4 + 3][row] = vb.w;
        }
        __syncthreads();
#pragma unroll
        for (int k = 0; k < 16; ++k) {
            float4 a0 = *(const float4*)&As[k][ty * 8];
            float4 a1 = *(const float4*)&As[k][ty * 8 + 4];
            float4 c0 = *(const float4*)&Bs[k][tx * 8];
            float4 c1 = *(const float4*)&Bs[k][tx * 8 + 4];
            float av[8] = {a0.x, a0.y, a0.z, a0.w, a1.x, a1.y, a1.z, a1.w};
            float bv[8] = {c0.x, c0.y, c0.z, c0.w, c1.x, c1.y, c1.z, c1.w};
#pragma unroll
            for (int i = 0; i < 8; ++i)
#pragma unroll
                for (int j = 0; j < 8; ++j)
                    acc[i][j] = fmaf(av[i], bv[j], acc[i][j]);
        }
        __syncthreads();
    }

    float bj[8];
#pragma unroll
    for (int j = 0; j < 8; ++j) bj[j] = bias[n0 + tx * 8 + j];
#pragma unroll
    for (int i = 0; i < 8; ++i) {
        const size_t m = (size_t)(m0 + ty * 8 + i);
        float4 o0, o1;
        o0.x = acc[i][0] + bj[0]; o0.y = acc[i][1] + bj[1];
        o0.z = acc[i][2] + bj[2]; o0.w = acc[i][3] + bj[3];
        o1.x = acc[i][4] + bj[4]; o1.y = acc[i][5] + bj[5];
        o1.z = acc[i][6] + bj[6]; o1.w = acc[i][7] + bj[7];
        *(float4*)&pre[m * G4 + n0 + tx * 8]     = o0;
        *(float4*)&pre[m * G4 + n0 + tx * 8 + 4] = o1;
    }
}

// ---------------------------------------------------------------------------
// Kernel B: BiLSTM recurrence. 256 blocks x 512 threads, 1 block/CU.
// chain = blk & 63, slice = blk >> 6  => slices of chain c are blocks
// {c, c+64, c+128, c+192}, all congruent mod 8 -> same XCD under round-robin
// placement. Verified AT RUNTIME via HW_REG_XCC_ID (s_getreg builtin, m09):
// all-equal -> FAST path (XCD-L2-local: sc0 h stores, sc0 flag polls + h
// loads, per-wave vmcnt(0) release). Distinct XCDs report distinct IDs, so
// an all-equal vote implies same XCD. Else -> agent-scope fallback.
// All h stores of a step are issued by wave 0 only; wave 0's
// s_waitcnt vmcnt(0) before its flag store orders them (vmcnt is per-wave).
// FAST spins are bounded (SPIN_LIMIT polls) then upgrade to agent-scope
// acquire, and an upgraded wait also routes the h-load through the
// agent-scope path — any coherence-model error becomes bounded-slow but
// CORRECT, never a hang and never a stale read.
// ---------------------------------------------------------------------------
template <int FAST>
__device__ __forceinline__ void lstm_loop(
    const float* __restrict__ wrow, const float* __restrict__ prebase,
    float* __restrict__ hout, int* __restrict__ flagp,
    float* __restrict__ h_lds, float* __restrict__ cg_lds,
    const int slice, const int dir, const int tid, const int j0) {
    // 128 weights (half of one gate row) into registers
    float wreg[128];
#pragma unroll
    for (int i = 0; i < 32; ++i) {
        float4 v = *(const float4*)&wrow[i * 4];
        wreg[i * 4 + 0] = v.x; wreg[i * 4 + 1] = v.y;
        wreg[i * 4 + 2] = v.z; wreg[i * 4 + 3] = v.w;
    }

    const int cl = tid >> 1;   // local gate-col 0..255
    const int kh = tid & 1;    // k-half
    float cstate = 0.f;        // valid for tid < 64
    if (tid < 256) h_lds[tid] = 0.f;

    const size_t TSTR = (size_t)NB * G4;
    float pv = prebase[(size_t)(dir ? (LSEQ - 1) : 0) * TSTR];

    for (int s = 0; s < LSEQ; ++s) {
        const int t = dir ? (LSEQ - 1 - s) : s;

        if (s > 0 && tid < 256) {
            const int w = tid >> 6;          // producer slice this wave reads
            const int* fp = flagp + w;
            bool upgraded = false;
            if (FAST) {
                int f, tries = 0;
                do {
                    if (++tries < SPIN_LIMIT) {
                        asm volatile(
                            "global_load_dword %0, %1, off sc0\n\t"
                            "s_waitcnt vmcnt(0)"
                            : "=v"(f) : "v"(fp) : "memory");
                    } else {  // insurance: never triggers if sc0 model holds
                        upgraded = true;
                        f = __hip_atomic_load(fp, __ATOMIC_ACQUIRE,
                                              __HIP_MEMORY_SCOPE_AGENT);
                    }
                } while (f < s);
            } else {
                while (__hip_atomic_load(fp, __ATOMIC_ACQUIRE,
                                         __HIP_MEMORY_SCOPE_AGENT) < s)
                    __builtin_amdgcn_s_sleep(1);
            }
            const int tprev = dir ? (t + 1) : (t - 1);
            const float* hp = hout + (size_t)tprev * D2 + tid;
            float hv;
            if (FAST && !upgraded) {
                // sc0: bypass L1, read the XCD L2 the producer stored to
                asm volatile(
                    "global_load_dword %0, %1, off sc0\n\t"
                    "s_waitcnt vmcnt(0)"
                    : "=v"(hv) : "v"(hp) : "memory");
            } else {
                hv = __hip_atomic_load(hp, __ATOMIC_RELAXED,
                                       __HIP_MEMORY_SCOPE_AGENT);
            }
            h_lds[tid] = hv;
        }
        __syncthreads();

        // 128-MAC half-row dot, 4 independent FMA chains
        float a0 = 0.f, a1 = 0.f, a2 = 0.f, a3 = 0.f;
#pragma unroll
        for (int kk = 0; kk < 32; ++kk) {
            float4 h4 = *(const float4*)&h_lds[kh * 128 + kk * 4];
            a0 = fmaf(wreg[kk * 4 + 0], h4.x, a0);
            a1 = fmaf(wreg[kk * 4 + 1], h4.y, a1);
            a2 = fmaf(wreg[kk * 4 + 2], h4.z, a2);
            a3 = fmaf(wreg[kk * 4 + 3], h4.w, a3);
        }
        float sacc = (a0 + a1) + (a2 + a3);
        sacc += __shfl_xor(sacc, 1);
        if (kh == 0) cg_lds[cl] = sacc + pv;
        __syncthreads();

        if (tid < 64) {
            const float xi = cg_lds[tid];
            const float xf = cg_lds[64 + tid];
            const float xg = cg_lds[128 + tid];
            const float xo = cg_lds[192 + tid];
            const float ii = 1.f / (1.f + expf(-xi));
            const float ff = 1.f / (1.f + expf(-xf));
            const float gg = tanhf(xg);
            const float oo = 1.f / (1.f + expf(-xo));
            cstate = ff * cstate + ii * gg;
            const float hh = oo * tanhf(cstate);
            float* sp = hout + (size_t)t * D2 + j0 + tid;
            if (FAST) {
                // sc0 store: bypass L1, land in XCD L2 (point of coherence)
                asm volatile("global_store_dword %0, %1, off sc0"
                             :: "v"(sp), "v"(hh) : "memory");
            } else {
                __hip_atomic_store(sp, hh, __ATOMIC_RELAXED,
                                   __HIP_MEMORY_SCOPE_AGENT);
            }
        }

        if (FAST) {
            asm volatile("s_waitcnt vmcnt(0)" ::: "memory");  // h stores at L2
            if (tid == 0) {
                const int val = s + 1;
                const int* fp = flagp + slice;
                asm volatile("global_store_dword %0, %1, off sc0"
                             :: "v"(fp), "v"(val) : "memory");
            }
        } else {
            if (tid == 0)
                __hip_atomic_store(flagp + slice, s + 1, __ATOMIC_RELEASE,
                                   __HIP_MEMORY_SCOPE_AGENT);
        }

        // prefetch next step's pre value; drained before use next iteration
        if (s + 1 < LSEQ) {
            const int tn = dir ? (LSEQ - 2 - s) : (s + 1);
            pv = prebase[(size_t)tn * TSTR];
        }
    }
}

__global__ __launch_bounds__(512, 2) void lstm_kernel(
    const float* __restrict__ w_hh_f, const float* __restrict__ w_hh_b,
    float* __restrict__ ws, float* __restrict__ out) {
    const int blk   = blockIdx.x;
    const int chain = blk & 63;    // slices of a chain are congruent mod 8
    const int slice = blk >> 6;
    const int dir   = chain >> 5;
    const int b     = chain & 31;
    const int j0    = slice * 64;
    const int tid   = threadIdx.x;

    const int cl = tid >> 1;
    const int g  = cl >> 6, ul = cl & 63;
    const int colg = g * 256 + j0 + ul;
    const int kh = tid & 1;

    const float* whh = dir ? w_hh_b : w_hh_f;
    const float* wrow = whh + (size_t)colg * HC + kh * 128;
    const float* prebase = ws + (size_t)dir * PRESZ + (size_t)b * G4 + colg;
    float* hout = out + LSTM_OFF + (size_t)b * LSEQ * D2 + dir * HC;

    int* syncbase = (int*)(ws + SYNC_INT_OFF);
    int* xcc_arr  = syncbase;        // 256 ints
    int* flags    = syncbase + 256;  // 256 ints
    int* flagp    = flags + chain * 4;

    // --- runtime XCD-placement agreement (correct under ANY placement) ---
    // All 256 blocks are co-resident (1 block/CU, 256 CUs), so this
    // agent-scope exchange always completes.
    const int xcc = (int)__builtin_amdgcn_s_getreg(GETREG_XCC_IMM);
    if (tid == 0)
        __hip_atomic_store(&xcc_arr[chain * 4 + slice], xcc + 1,
                           __ATOMIC_RELEASE, __HIP_MEMORY_SCOPE_AGENT);
    __shared__ int xs[4];
    if (tid < 4) {
        int v;
        do {
            v = __hip_atomic_load(&xcc_arr[chain * 4 + tid], __ATOMIC_ACQUIRE,
                                  __HIP_MEMORY_SCOPE_AGENT);
            if (v == 0) __builtin_amdgcn_s_sleep(2);
        } while (v == 0);
        xs[tid] = v;
    }
    __shared__ __align__(16) float h_lds[256];
    __shared__ __align__(16) float cg_lds[256];
    __syncthreads();
    const bool fast = (xs[0] == xs[1]) && (xs[1] == xs[2]) && (xs[2] == xs[3]);

    if (fast)
        lstm_loop<1>(wrow, prebase, hout, flagp, h_lds, cg_lds, slice, dir, tid, j0);
    else
        lstm_loop<0>(wrow, prebase, hout, flagp, h_lds, cg_lds, slice, dir, tid, j0);
}

// ---------------------------------------------------------------------------
// Kernel C: align = lstm_out · lstm_outᵀ / sqrt(2H), fused top-3 per row.
// ---------------------------------------------------------------------------
__global__ __launch_bounds__(256) void align_topk_kernel(
    const float* __restrict__ outl, float* __restrict__ coo,
    float* __restrict__ vals) {
    const int b  = blockIdx.x;
    const int rt = blockIdx.y;
    const int r0 = rt * 64;
    const float* __restrict__ base = outl + (size_t)b * LSEQ * D2;

    const int tid = threadIdx.x;
    const int tx = tid & 15, ty = tid >> 4;

    __shared__ __align__(16) float As[32][68];
    __shared__ __align__(16) float Bs[32][68];
    __shared__ __align__(16) float tile[64][65];

    float v0 = -INFINITY, v1 = -INFINITY, v2 = -INFINITY;
    int i0 = 0, i1 = 0, i2 = 0;

    for (int ct = 0; ct < 16; ++ct) {
        const int c0 = ct * 64;
        float acc[4][4];
#pragma unroll
        for (int i = 0; i < 4; ++i)
#pragma unroll
            for (int j = 0; j < 4; ++j) acc[i][j] = 0.f;

        for (int k0 = 0; k0 < D2; k0 += 32) {
#pragma unroll
            for (int r = 0; r < 2; ++r) {
                const int e = r * 256 + tid;
                const int row = e >> 3, kq = e & 7;
                float4 va = *(const float4*)&base[(size_t)(r0 + row) * D2 + k0 + kq * 4];
                As[kq * 4 + 0][row] = va.x; As[kq * 4 + 1][row] = va.y;
                As[kq * 4 + 2][row] = va.z; As[kq * 4 + 3][row] = va.w;
                float4 vb = *(const float4*)&base[(size_t)(c0 + row) * D2 + k0 + kq * 4];
                Bs[kq * 4 + 0][row] = vb.x; Bs[kq * 4 + 1][row] = vb.y;
                Bs[kq * 4 + 2][row] = vb.z; Bs[kq * 4 + 3][row] = vb.w;
            }
            __syncthreads();
#pragma unroll
            for (int k = 0; k < 32; ++k) {
                float4 a = *(const float4*)&As[k][ty * 4];
                float4 c = *(const float4*)&Bs[k][tx * 4];
                float av[4] = {a.x, a.y, a.z, a.w};
                float bv[4] = {c.x, c.y, c.z, c.w};
#pragma unroll
                for (int i = 0; i < 4; ++i)
#pragma unroll
                    for (int j = 0; j < 4; ++j)
                        acc[i][j] = fmaf(av[i], bv[j], acc[i][j]);
            }
            __syncthreads();
        }

#pragma unroll
        for (int i = 0; i < 4; ++i)
#pragma unroll
            for (int j = 0; j < 4; ++j)
                tile[ty * 4 + i][tx * 4 + j] = acc[i][j] * ALIGN_SCALE;
        __syncthreads();

        if (tid < 64) {
            for (int j = 0; j < 64; ++j) {
                const float v = tile[tid][j];
                const int idx = c0 + j;
                if (v > v0) { v2 = v1; i2 = i1; v1 = v0; i1 = i0; v0 = v; i0 = idx; }
                else if (v > v1) { v2 = v1; i2 = i1; v1 = v; i1 = idx; }
                else if (v > v2) { v2 = v; i2 = idx; }
            }
        }
        __syncthreads();
    }

    if (tid < 64) {
        const int l = r0 + tid;
        float* vp = vals + ((size_t)b * LSEQ + l) * TOPK;
        vp[0] = v0; vp[1] = v1; vp[2] = v2;
        float* c0p = coo + ((size_t)b * 2 + 0) * (LSEQ * TOPK) + l * TOPK;
        float* c1p = coo + ((size_t)b * 2 + 1) * (LSEQ * TOPK) + l * TOPK;
        c0p[0] = (float)i0; c0p[1] = (float)i1; c0p[2] = (float)i2;
        c1p[0] = (float)l;  c1p[1] = (float)l;  c1p[2] = (float)l;
    }
}

// ---------------------------------------------------------------------------
extern "C" void kernel_launch(void* const* d_in, const int* in_sizes, int n_in,
                              void* d_out, int out_size, void* d_ws, size_t ws_size,
                              hipStream_t stream) {
    const float* x      = (const float*)d_in[0];
    const float* w_ih_f = (const float*)d_in[1];
    const float* w_hh_f = (const float*)d_in[2];
    const float* b_f    = (const float*)d_in[3];
    const float* w_ih_b = (const float*)d_in[4];
    const float* w_hh_b = (const float*)d_in[5];
    const float* b_b    = (const float*)d_in[6];

    float* out = (float*)d_out;
    float* ws  = (float*)d_ws;
    int* syncbase = (int*)(ws + SYNC_INT_OFF);

    zero_sync_kernel<<<1, 512, 0, stream>>>(syncbase);

    proj_kernel<<<dim3((LSEQ * NB) / 128, G4 / 128, 2), 256, 0, stream>>>(
        x, w_ih_f, b_f, w_ih_b, b_b, ws);

    lstm_kernel<<<256, 512, 0, stream>>>(w_hh_f, w_hh_b, ws, out);

    align_topk_kernel<<<dim3(NB, LSEQ / 64), 256, 0, stream>>>(
        out + LSTM_OFF, out + COO_OFF, out + VALS_OFF);
}